// Round 3
// baseline (438.722 us; speedup 1.0000x reference)
//
#include <hip/hip_runtime.h>
#include <hip/hip_bf16.h>

typedef __attribute__((ext_vector_type(8))) short short8;
typedef __attribute__((ext_vector_type(4))) float f32x4;

__device__ inline unsigned short f2bf(float f) {
  __hip_bfloat16 h = __float2bfloat16(f);
  return *reinterpret_cast<unsigned short*>(&h);
}
__device__ inline float bf2f(unsigned short u) {
  union { unsigned u; float f; } v; v.u = ((unsigned)u) << 16;
  return v.f;
}

#define GLOAD_LDS16(g, l)                                          \
  __builtin_amdgcn_global_load_lds(                                \
      (const __attribute__((address_space(1))) void*)(g),          \
      (__attribute__((address_space(3))) void*)(l), 16, 0, 0)

// ---------------- f32 -> bf16 bulk convert (8 elems/thread) ----------------
__global__ void f32_to_bf16(const float* __restrict__ in,
                            unsigned short* __restrict__ out, int n8) {
  int i = blockIdx.x * 256 + threadIdx.x;
  if (i >= n8) return;
  const float4* p = (const float4*)in + (size_t)i * 2;
  float4 a = p[0], b = p[1];
  short8 v;
  v[0] = f2bf(a.x); v[1] = f2bf(a.y); v[2] = f2bf(a.z); v[3] = f2bf(a.w);
  v[4] = f2bf(b.x); v[5] = f2bf(b.y); v[6] = f2bf(b.z); v[7] = f2bf(b.w);
  *((short8*)out + i) = v;
}

// ---- m97-structure GEMM: C[M][N] = A[M][K] * B[N][K]^T, bf16 in, 128^2 tile ----
template <bool OUT_F32>
__global__ __launch_bounds__(256, 3)
void gemm_bt_bf16(const unsigned short* __restrict__ A,
                  const unsigned short* __restrict__ B,
                  void* __restrict__ Cp, int M, int N, int K) {
  __shared__ __align__(16) unsigned short As[128 * 32];
  __shared__ __align__(16) unsigned short Bs[128 * 32];
  const int t = threadIdx.x;
  const int lane = t & 63, w = t >> 6;
  const int wr = w >> 1, wc = w & 1;
  const int r16 = lane & 15, kg = lane >> 4;
  const int bm = blockIdx.x, bn = blockIdx.y;

  const int srow = w * 16 + (lane >> 2);
  const int scol = (lane & 3) * 8;

  const unsigned short* Ag = A + (size_t)(bm * 128) * K;
  const unsigned short* Bg = B + (size_t)(bn * 128) * K;

  f32x4 acc[4][4] = {};

  for (int k0 = 0; k0 < K; k0 += 32) {
    __syncthreads();
#pragma unroll
    for (int i = 0; i < 2; ++i) {
      GLOAD_LDS16(Ag + (size_t)(i * 64 + srow) * K + k0 + scol,
                  As + i * 2048 + w * 512);
      GLOAD_LDS16(Bg + (size_t)(i * 64 + srow) * K + k0 + scol,
                  Bs + i * 2048 + w * 512);
    }
    __syncthreads();

    short8 a[4], b[4];
#pragma unroll
    for (int m = 0; m < 4; ++m)
      a[m] = *(const short8*)&As[(wr * 64 + m * 16 + r16) * 32 + kg * 8];
#pragma unroll
    for (int n = 0; n < 4; ++n)
      b[n] = *(const short8*)&Bs[(wc * 64 + n * 16 + r16) * 32 + kg * 8];
#pragma unroll
    for (int m = 0; m < 4; ++m)
#pragma unroll
      for (int n = 0; n < 4; ++n)
        acc[m][n] = __builtin_amdgcn_mfma_f32_16x16x32_bf16(a[m], b[n], acc[m][n], 0, 0, 0);
  }

#pragma unroll
  for (int m = 0; m < 4; ++m) {
#pragma unroll
    for (int n = 0; n < 4; ++n) {
#pragma unroll
      for (int j = 0; j < 4; ++j) {
        int row = bm * 128 + wr * 64 + m * 16 + kg * 4 + j;
        int col = bn * 128 + wc * 64 + n * 16 + r16;
        if (OUT_F32) ((float*)Cp)[(size_t)row * N + col] = acc[m][n][j];
        else ((unsigned short*)Cp)[(size_t)row * N + col] = f2bf(acc[m][n][j]);
      }
    }
  }
}

// ---------------- RoPE for Q (with 1/sqrt(hs)) and K; scatter ----------------
__global__ void rope_qk(const unsigned short* __restrict__ qkv,
                        const float* __restrict__ cosb, const float* __restrict__ sinb,
                        unsigned short* __restrict__ Q, unsigned short* __restrict__ K) {
  int pair = blockIdx.x * 4 + (threadIdx.x >> 6);
  int l = threadIdx.x & 63;
  int t = pair / 40, slot = pair - t * 40;
  const unsigned short* src;
  unsigned short* dst;
  float scale;
  if (slot < 32) {
    int g = slot >> 2, j = slot & 3;
    src = qkv + (size_t)t * 6144 + g * 768 + j * 128;
    dst = Q + ((size_t)slot * 2048 + t) * 128;
    scale = 0.08838834764831845f;  // 1/sqrt(128)
  } else {
    int g = slot - 32;
    src = qkv + (size_t)t * 6144 + g * 768 + 512;
    dst = K + ((size_t)g * 2048 + t) * 128;
    scale = 1.0f;
  }
  float x1 = bf2f(src[l]), x2 = bf2f(src[64 + l]);
  float c1 = cosb[t * 128 + l], s1 = sinb[t * 128 + l];
  float c2 = cosb[t * 128 + 64 + l], s2 = sinb[t * 128 + 64 + l];
  dst[l]      = f2bf((x1 * c1 - x2 * s1) * scale);
  dst[64 + l] = f2bf((x2 * c2 + x1 * s2) * scale);
}

// ---------------- Vt[g][d][t] = qkv[t][g*768+640+d] ----------------
__global__ void transpose_v(const unsigned short* __restrict__ qkv,
                            unsigned short* __restrict__ Vt) {
  __shared__ __align__(16) unsigned short tile[64][136];
  int g = blockIdx.y, t0 = blockIdx.x * 64;
  int th = threadIdx.x;
  int r = th >> 2, c0 = (th & 3) * 32;
  const unsigned short* src = qkv + (size_t)(t0 + r) * 6144 + g * 768 + 640 + c0;
#pragma unroll
  for (int i = 0; i < 4; ++i)
    *(short8*)&tile[r][c0 + i * 8] = *(const short8*)(src + i * 8);
  __syncthreads();
  int d = th >> 1, tc = (th & 1) * 32;
  unsigned short* dst = Vt + (size_t)(g * 128 + d) * 2048 + t0 + tc;
#pragma unroll
  for (int j = 0; j < 32; ++j) dst[j] = tile[tc + j][d];
}

// ---------------- Flash attention v2: gload_lds + dbuf + 1 barrier/tile ----------------
// 1 block = 1 head x 64 q-rows (4 waves x 16 rows). KV tile = 64, double-buffered.
__global__ __launch_bounds__(256, 2)
void flash_attn(const unsigned short* __restrict__ Q, const unsigned short* __restrict__ K,
                const unsigned short* __restrict__ Vt, unsigned short* __restrict__ Y) {
  __shared__ __align__(16) unsigned short Ksm[2][64 * 128];   // [kv][d], XOR-swizzled (16B chunks)
  __shared__ __align__(16) unsigned short Vsm[2][128 * 64];   // [d][kv], XOR-swizzled
  __shared__ __align__(16) unsigned short Psm[4][16][72];     // per-wave P, padded

  const int h = blockIdx.y, g = h >> 2;
  const int q0 = (gridDim.x - 1 - blockIdx.x) * 64;  // heavy tiles dispatch first
  const int t = threadIdx.x, lane = t & 63, w = t >> 6;
  const int r16 = lane & 15, kg = lane >> 4;

  const unsigned short* Kg = K + (size_t)g * 2048 * 128;
  const unsigned short* Vg = Vt + (size_t)g * 128 * 2048;

  // per-lane staging geometry (pre-swizzled GLOBAL source, linear LDS dest)
  const int krl = lane >> 4, kc = lane & 15;  // K: 4 rows/issue, 16 chunks/row
  const int vrl = lane >> 3, vc = lane & 7;   // V: 8 rows/issue, 8 chunks/row

  // stage KV tile at kv offset kvs into buffer b
  auto stage = [&](int kvs, int b) {
#pragma unroll
    for (int i = 0; i < 4; ++i) {
      int row = w * 16 + i * 4 + krl;
      int sc = kc ^ (row & 7);
      GLOAD_LDS16(Kg + (size_t)(kvs + row) * 128 + sc * 8,
                  &Ksm[b][(w * 16 + i * 4) * 128]);
    }
#pragma unroll
    for (int i = 0; i < 4; ++i) {
      int d = w * 32 + i * 8 + vrl;
      int sc = vc ^ (d & 7);
      GLOAD_LDS16(Vg + (size_t)d * 2048 + kvs + sc * 8,
                  &Vsm[b][(w * 32 + i * 8) * 64]);
    }
  };

  short8 qf[4];
  const unsigned short* qrow = Q + ((size_t)h * 2048 + q0 + w * 16 + r16) * 128;
#pragma unroll
  for (int kk = 0; kk < 4; ++kk) qf[kk] = *(const short8*)(qrow + kk * 32 + kg * 8);

  f32x4 o[8] = {};
  float mrow[4] = {-1e30f, -1e30f, -1e30f, -1e30f};
  float lrow[4] = {0.f, 0.f, 0.f, 0.f};

  const int nt = q0 / 64 + 1;
  stage(0, 0);

  for (int kt = 0; kt < nt; ++kt) {
    const int b = kt & 1;
    const int kv0 = kt * 64;
    __syncthreads();  // drains vmcnt: LDS[b] ready; all waves done reading LDS[b^1]
    if (kt + 1 < nt) stage((kt + 1) * 64, b ^ 1);

    // S = Q K^T
    f32x4 s[4] = {};
    __builtin_amdgcn_s_setprio(1);
#pragma unroll
    for (int n = 0; n < 4; ++n) {
      int kvcol = n * 16 + r16;
#pragma unroll
      for (int kk = 0; kk < 4; ++kk) {
        short8 kf = *(const short8*)__builtin_assume_aligned(
            &Ksm[b][kvcol * 128 + ((kk * 32 + kg * 8) ^ ((kvcol & 7) << 3))], 16);
        s[n] = __builtin_amdgcn_mfma_f32_16x16x32_bf16(qf[kk], kf, s[n], 0, 0, 0);
      }
    }
    __builtin_amdgcn_s_setprio(0);

    const int qglob = q0 + w * 16 + kg * 4;
    if (kv0 + 63 > q0 + w * 16) {  // wave-uniform: tile touches the diagonal
#pragma unroll
      for (int n = 0; n < 4; ++n) {
        int kvg = kv0 + n * 16 + r16;
#pragma unroll
        for (int j = 0; j < 4; ++j)
          if (kvg > qglob + j) s[n][j] = -1e30f;
      }
    }

    float rmax[4];
#pragma unroll
    for (int j = 0; j < 4; ++j)
      rmax[j] = fmaxf(fmaxf(s[0][j], s[1][j]), fmaxf(s[2][j], s[3][j]));
#pragma unroll
    for (int j = 0; j < 4; ++j)
#pragma unroll
      for (int off = 1; off < 16; off <<= 1)
        rmax[j] = fmaxf(rmax[j], __shfl_xor(rmax[j], off));

    // exact defer-rescale: skip o-rescale when no row's max grew (wave-uniform)
    bool grew = (rmax[0] > mrow[0]) | (rmax[1] > mrow[1]) |
                (rmax[2] > mrow[2]) | (rmax[3] > mrow[3]);
    float rsum[4] = {0.f, 0.f, 0.f, 0.f};
    if (__builtin_amdgcn_ballot_w64(grew)) {
      float fac[4];
#pragma unroll
      for (int j = 0; j < 4; ++j) {
        float mnew = fmaxf(mrow[j], rmax[j]);
        fac[j] = __expf(mrow[j] - mnew);
        mrow[j] = mnew;
      }
#pragma unroll
      for (int f = 0; f < 8; ++f)
#pragma unroll
        for (int j = 0; j < 4; ++j) o[f][j] *= fac[j];
#pragma unroll
      for (int j = 0; j < 4; ++j) lrow[j] *= fac[j];
    }
#pragma unroll
    for (int n = 0; n < 4; ++n)
#pragma unroll
      for (int j = 0; j < 4; ++j) {
        float p = __expf(s[n][j] - mrow[j]);
        rsum[j] += p;
        Psm[w][kg * 4 + j][n * 16 + r16] = f2bf(p);
      }
#pragma unroll
    for (int j = 0; j < 4; ++j) {
#pragma unroll
      for (int off = 1; off < 16; off <<= 1) rsum[j] += __shfl_xor(rsum[j], off);
      lrow[j] += rsum[j];
    }

    // O += P V
    __builtin_amdgcn_s_setprio(1);
#pragma unroll
    for (int kk = 0; kk < 2; ++kk) {
      short8 pf = *(const short8*)__builtin_assume_aligned(&Psm[w][r16][kk * 32 + kg * 8], 16);
#pragma unroll
      for (int f = 0; f < 8; ++f) {
        int d = f * 16 + r16;
        short8 vf = *(const short8*)__builtin_assume_aligned(
            &Vsm[b][d * 64 + ((kk * 32 + kg * 8) ^ ((d & 7) << 3))], 16);
        o[f] = __builtin_amdgcn_mfma_f32_16x16x32_bf16(pf, vf, o[f], 0, 0, 0);
      }
    }
    __builtin_amdgcn_s_setprio(0);
  }

#pragma unroll
  for (int j = 0; j < 4; ++j) {
    float inv = 1.f / lrow[j];
    int row = q0 + w * 16 + kg * 4 + j;
    unsigned short* yr = Y + (size_t)row * 4096 + h * 128;
#pragma unroll
    for (int f = 0; f < 8; ++f) yr[f * 16 + r16] = f2bf(o[f][j] * inv);
  }
}

extern "C" void kernel_launch(void* const* d_in, const int* in_sizes, int n_in,
                              void* d_out, int out_size, void* d_ws, size_t ws_size,
                              hipStream_t stream) {
  const float* x      = (const float*)d_in[0];
  const float* cosb   = (const float*)d_in[1];
  const float* sinb   = (const float*)d_in[2];
  const float* w_attn = (const float*)d_in[3];
  const float* w_proj = (const float*)d_in[4];
  float* out = (float*)d_out;

  char* ws = (char*)d_ws;
  const size_t MB = 1024 * 1024;
  unsigned short* Xb  = (unsigned short*)(ws);
  unsigned short* Wa  = (unsigned short*)(ws + 16 * MB);
  unsigned short* Wp  = (unsigned short*)(ws);            // after gemm1
  unsigned short* Qb  = (unsigned short*)(ws + 32 * MB);  // after gemm1
  unsigned short* Kb  = (unsigned short*)(ws + 48 * MB);  // after gemm1
  unsigned short* Vt  = (unsigned short*)(ws + 52 * MB);  // after gemm1
  unsigned short* qkv = (unsigned short*)(ws + 64 * MB);
  unsigned short* Yb  = (unsigned short*)(ws + 64 * MB);  // after rope+transpose

  f32_to_bf16<<<4096, 256, 0, stream>>>(x, Xb, 2048 * 4096 / 8);
  f32_to_bf16<<<12288, 256, 0, stream>>>(w_attn, Wa, 6144 * 4096 / 8);
  gemm_bt_bf16<false><<<dim3(16, 48), 256, 0, stream>>>(Xb, Wa, qkv, 2048, 6144, 4096);
  rope_qk<<<20480, 256, 0, stream>>>(qkv, cosb, sinb, Qb, Kb);
  transpose_v<<<dim3(32, 8), 256, 0, stream>>>(qkv, Vt);
  f32_to_bf16<<<8192, 256, 0, stream>>>(w_proj, Wp, 4096 * 4096 / 8);
  flash_attn<<<dim3(32, 32), 256, 0, stream>>>(Qb, Kb, Vt, Yb);
  gemm_bt_bf16<true><<<dim3(16, 32), 256, 0, stream>>>(Yb, Wp, out, 2048, 4096, 4096);
}

// Round 4
// 351.615 us; speedup vs baseline: 1.2477x; 1.2477x over previous
//
#include <hip/hip_runtime.h>
#include <hip/hip_bf16.h>

typedef __attribute__((ext_vector_type(8))) short short8;
typedef __attribute__((ext_vector_type(4))) float f32x4;

__device__ inline unsigned short f2bf(float f) {
  __hip_bfloat16 h = __float2bfloat16(f);
  return *reinterpret_cast<unsigned short*>(&h);
}
__device__ inline float bf2f(unsigned short u) {
  union { unsigned u; float f; } v; v.u = ((unsigned)u) << 16;
  return v.f;
}

#define GLOAD_LDS16(g, l)                                          \
  __builtin_amdgcn_global_load_lds(                                \
      (const __attribute__((address_space(1))) void*)(g),          \
      (__attribute__((address_space(3))) void*)(l), 16, 0, 0)

// ---------------- f32 -> bf16 bulk convert (8 elems/thread) ----------------
__global__ void f32_to_bf16(const float* __restrict__ in,
                            unsigned short* __restrict__ out, int n8) {
  int i = blockIdx.x * 256 + threadIdx.x;
  if (i >= n8) return;
  const float4* p = (const float4*)in + (size_t)i * 2;
  float4 a = p[0], b = p[1];
  short8 v;
  v[0] = f2bf(a.x); v[1] = f2bf(a.y); v[2] = f2bf(a.z); v[3] = f2bf(a.w);
  v[4] = f2bf(b.x); v[5] = f2bf(b.y); v[6] = f2bf(b.z); v[7] = f2bf(b.w);
  *((short8*)out + i) = v;
}

// ---- m97-structure GEMM: C[M][N] = A[M][K] * B[N][K]^T, bf16 in, 128^2 tile ----
template <bool OUT_F32>
__global__ __launch_bounds__(256, 3)
void gemm_bt_bf16(const unsigned short* __restrict__ A,
                  const unsigned short* __restrict__ B,
                  void* __restrict__ Cp, int M, int N, int K) {
  __shared__ __align__(16) unsigned short As[128 * 32];
  __shared__ __align__(16) unsigned short Bs[128 * 32];
  const int t = threadIdx.x;
  const int lane = t & 63, w = t >> 6;
  const int wr = w >> 1, wc = w & 1;
  const int r16 = lane & 15, kg = lane >> 4;
  const int bm = blockIdx.x, bn = blockIdx.y;

  const int srow = w * 16 + (lane >> 2);
  const int scol = (lane & 3) * 8;

  const unsigned short* Ag = A + (size_t)(bm * 128) * K;
  const unsigned short* Bg = B + (size_t)(bn * 128) * K;

  f32x4 acc[4][4] = {};

  for (int k0 = 0; k0 < K; k0 += 32) {
    __syncthreads();
#pragma unroll
    for (int i = 0; i < 2; ++i) {
      GLOAD_LDS16(Ag + (size_t)(i * 64 + srow) * K + k0 + scol,
                  As + i * 2048 + w * 512);
      GLOAD_LDS16(Bg + (size_t)(i * 64 + srow) * K + k0 + scol,
                  Bs + i * 2048 + w * 512);
    }
    __syncthreads();

    short8 a[4], b[4];
#pragma unroll
    for (int m = 0; m < 4; ++m)
      a[m] = *(const short8*)&As[(wr * 64 + m * 16 + r16) * 32 + kg * 8];
#pragma unroll
    for (int n = 0; n < 4; ++n)
      b[n] = *(const short8*)&Bs[(wc * 64 + n * 16 + r16) * 32 + kg * 8];
#pragma unroll
    for (int m = 0; m < 4; ++m)
#pragma unroll
      for (int n = 0; n < 4; ++n)
        acc[m][n] = __builtin_amdgcn_mfma_f32_16x16x32_bf16(a[m], b[n], acc[m][n], 0, 0, 0);
  }

#pragma unroll
  for (int m = 0; m < 4; ++m) {
#pragma unroll
    for (int n = 0; n < 4; ++n) {
#pragma unroll
      for (int j = 0; j < 4; ++j) {
        int row = bm * 128 + wr * 64 + m * 16 + kg * 4 + j;
        int col = bn * 128 + wc * 64 + n * 16 + r16;
        if (OUT_F32) ((float*)Cp)[(size_t)row * N + col] = acc[m][n][j];
        else ((unsigned short*)Cp)[(size_t)row * N + col] = f2bf(acc[m][n][j]);
      }
    }
  }
}

// ---------------- RoPE for Q (with 1/sqrt(hs)) and K; scatter ----------------
__global__ void rope_qk(const unsigned short* __restrict__ qkv,
                        const float* __restrict__ cosb, const float* __restrict__ sinb,
                        unsigned short* __restrict__ Q, unsigned short* __restrict__ K) {
  int pair = blockIdx.x * 4 + (threadIdx.x >> 6);
  int l = threadIdx.x & 63;
  int t = pair / 40, slot = pair - t * 40;
  const unsigned short* src;
  unsigned short* dst;
  float scale;
  if (slot < 32) {
    int g = slot >> 2, j = slot & 3;
    src = qkv + (size_t)t * 6144 + g * 768 + j * 128;
    dst = Q + ((size_t)slot * 2048 + t) * 128;
    scale = 0.08838834764831845f;  // 1/sqrt(128)
  } else {
    int g = slot - 32;
    src = qkv + (size_t)t * 6144 + g * 768 + 512;
    dst = K + ((size_t)g * 2048 + t) * 128;
    scale = 1.0f;
  }
  float x1 = bf2f(src[l]), x2 = bf2f(src[64 + l]);
  float c1 = cosb[t * 128 + l], s1 = sinb[t * 128 + l];
  float c2 = cosb[t * 128 + 64 + l], s2 = sinb[t * 128 + 64 + l];
  dst[l]      = f2bf((x1 * c1 - x2 * s1) * scale);
  dst[64 + l] = f2bf((x2 * c2 + x1 * s2) * scale);
}

// ---------------- Vt[g][d][t] = qkv[t][g*768+640+d] ----------------
__global__ void transpose_v(const unsigned short* __restrict__ qkv,
                            unsigned short* __restrict__ Vt) {
  __shared__ __align__(16) unsigned short tile[64][136];
  int g = blockIdx.y, t0 = blockIdx.x * 64;
  int th = threadIdx.x;
  int r = th >> 2, c0 = (th & 3) * 32;
  const unsigned short* src = qkv + (size_t)(t0 + r) * 6144 + g * 768 + 640 + c0;
#pragma unroll
  for (int i = 0; i < 4; ++i)
    *(short8*)&tile[r][c0 + i * 8] = *(const short8*)(src + i * 8);
  __syncthreads();
  int d = th >> 1, tc = (th & 1) * 32;
  unsigned short* dst = Vt + (size_t)(g * 128 + d) * 2048 + t0 + tc;
#pragma unroll
  for (int j = 0; j < 32; ++j) dst[j] = tile[tc + j][d];
}

// ---------------- Flash attention v3: swapped QK^T, in-register softmax ----------------
// 1 block = 1 head x TWO paired q-tiles (i, 31-i): exactly 33 KV tiles per block.
// 4 waves x 16 q-rows. KV tile = 64, double-buffered, gload_lds, 1 barrier/tile.
__global__ __launch_bounds__(256, 2)
void flash_attn(const unsigned short* __restrict__ Q, const unsigned short* __restrict__ K,
                const unsigned short* __restrict__ Vt, unsigned short* __restrict__ Y) {
  __shared__ __align__(16) unsigned short Ksm[2][64 * 128];   // [kv][d], XOR-swizzled
  __shared__ __align__(16) unsigned short Vsm[2][128 * 64];   // [d][kv], XOR-swizzled

  const int h = blockIdx.y, g = h >> 2;
  const int t = threadIdx.x, lane = t & 63, w = t >> 6;
  const int r16 = lane & 15, kg = lane >> 4;
  const bool odd = kg & 1;
  const bool hi = kg >> 1;
  const bool useswap = odd ^ hi;  // lanes kg=1,2 take the xor-32 exchanged data

  const unsigned short* Kg = K + (size_t)g * 2048 * 128;
  const unsigned short* Vg = Vt + (size_t)g * 128 * 2048;

  const int krl = lane >> 4, kc = lane & 15;
  const int vrl = lane >> 3, vc = lane & 7;

  auto stage = [&](int kvs, int b) {
#pragma unroll
    for (int i = 0; i < 4; ++i) {
      int row = w * 16 + i * 4 + krl;
      int sc = kc ^ (row & 7);
      GLOAD_LDS16(Kg + (size_t)(kvs + row) * 128 + sc * 8,
                  &Ksm[b][(w * 16 + i * 4) * 128]);
    }
#pragma unroll
    for (int i = 0; i < 4; ++i) {
      int d = w * 32 + i * 8 + vrl;
      int sc = vc ^ (d & 7);
      GLOAD_LDS16(Vg + (size_t)d * 2048 + kvs + sc * 8,
                  &Vsm[b][(w * 32 + i * 8) * 64]);
    }
  };

  auto process = [&](int q0) {
    short8 qf[4];
    const unsigned short* qrow = Q + ((size_t)h * 2048 + q0 + w * 16 + r16) * 128;
#pragma unroll
    for (int kk = 0; kk < 4; ++kk) qf[kk] = *(const short8*)(qrow + kk * 32 + kg * 8);

    f32x4 o[8] = {};
    float mrow = -1e30f, lrow = 0.f;
    const int qg = q0 + w * 16 + r16;  // this lane's q-row
    const int nt = q0 / 64 + 1;

    __syncthreads();  // previous phase done with all LDS buffers
    stage(0, 0);

    for (int kt = 0; kt < nt; ++kt) {
      const int b = kt & 1;
      const int kv0 = kt * 64;
      __syncthreads();  // vmcnt drained: LDS[b] ready; all waves done with LDS[b^1]
      if (kt + 1 < nt) stage((kt + 1) * 64, b ^ 1);

      // S^T = K Q^T : lane holds S[q = qg][kv = kv0 + n*16 + kg*4 + j]
      f32x4 s[4] = {};
      __builtin_amdgcn_s_setprio(1);
#pragma unroll
      for (int n = 0; n < 4; ++n) {
        int kr = n * 16 + r16;
#pragma unroll
        for (int kk = 0; kk < 4; ++kk) {
          short8 kf = *(const short8*)__builtin_assume_aligned(
              &Ksm[b][kr * 128 + ((kk * 32 + kg * 8) ^ ((kr & 7) << 3))], 16);
          s[n] = __builtin_amdgcn_mfma_f32_16x16x32_bf16(kf, qf[kk], s[n], 0, 0, 0);
        }
      }
      __builtin_amdgcn_s_setprio(0);

      if (kv0 + 63 > q0 + w * 16) {  // wave-uniform: tile touches the diagonal
#pragma unroll
        for (int n = 0; n < 4; ++n)
#pragma unroll
          for (int j = 0; j < 4; ++j)
            if (kv0 + n * 16 + kg * 4 + j > qg) s[n][j] = -1e30f;
      }

      // row max: in-lane 16 + 2-stage cross-kg reduce
      float rmax = -1e30f;
#pragma unroll
      for (int n = 0; n < 4; ++n)
#pragma unroll
        for (int j = 0; j < 4; ++j) rmax = fmaxf(rmax, s[n][j]);
      rmax = fmaxf(rmax, __shfl_xor(rmax, 16));
      rmax = fmaxf(rmax, __shfl_xor(rmax, 32));

      // exact defer-rescale: skip when no row's max grew
      if (__builtin_amdgcn_ballot_w64(rmax > mrow)) {
        float mnew = fmaxf(mrow, rmax);
        float fac = __expf(mrow - mnew);
        mrow = mnew;
        lrow *= fac;
        float fj[4];
#pragma unroll
        for (int j = 0; j < 4; ++j) fj[j] = __shfl(fac, kg * 4 + j);
#pragma unroll
        for (int f = 0; f < 8; ++f)
#pragma unroll
          for (int j = 0; j < 4; ++j) o[f][j] *= fj[j];
      }

      // exp + row sum (in-lane + 2-stage)
      float p[4][4];
      float rs = 0.f;
#pragma unroll
      for (int n = 0; n < 4; ++n)
#pragma unroll
        for (int j = 0; j < 4; ++j) {
          p[n][j] = __expf(s[n][j] - mrow);
          rs += p[n][j];
        }
      rs += __shfl_xor(rs, 16);
      rs += __shfl_xor(rs, 32);
      lrow += rs;

      // pack P to bf16 pairs: bpk[n][i] = (kv 16n+4kg+2i, +2i+1)
      unsigned bpk[4][2], xpk[4][2];
#pragma unroll
      for (int n = 0; n < 4; ++n)
#pragma unroll
        for (int i = 0; i < 2; ++i)
          bpk[n][i] = (unsigned)f2bf(p[n][2 * i]) | ((unsigned)f2bf(p[n][2 * i + 1]) << 16);
#pragma unroll
      for (int n = 0; n < 4; ++n)
#pragma unroll
        for (int i = 0; i < 2; ++i) xpk[n][i] = __shfl_xor(bpk[n][i], 16);

      // pair-ordered: pl = pair-low (m = kg&~1), ph = pair-high (m = kg|1)
      unsigned pl[4][2], ph[4][2];
#pragma unroll
      for (int n = 0; n < 4; ++n)
#pragma unroll
        for (int i = 0; i < 2; ++i) {
          pl[n][i] = odd ? xpk[n][i] : bpk[n][i];
          ph[n][i] = odd ? bpk[n][i] : xpk[n][i];
        }

      // keep: n = 2kk + hi ; send: n = 2kk + !hi ; swap across kg^2
      short8 pa[2];
#pragma unroll
      for (int kk = 0; kk < 2; ++kk) {
        unsigned kp0 = hi ? pl[2 * kk + 1][0] : pl[2 * kk][0];
        unsigned kp1 = hi ? pl[2 * kk + 1][1] : pl[2 * kk][1];
        unsigned kp2 = hi ? ph[2 * kk + 1][0] : ph[2 * kk][0];
        unsigned kp3 = hi ? ph[2 * kk + 1][1] : ph[2 * kk][1];
        unsigned sd0 = hi ? pl[2 * kk][0] : pl[2 * kk + 1][0];
        unsigned sd1 = hi ? pl[2 * kk][1] : pl[2 * kk + 1][1];
        unsigned sd2 = hi ? ph[2 * kk][0] : ph[2 * kk + 1][0];
        unsigned sd3 = hi ? ph[2 * kk][1] : ph[2 * kk + 1][1];
        unsigned g0 = __shfl_xor(sd0, 32), g1 = __shfl_xor(sd1, 32);
        unsigned g2 = __shfl_xor(sd2, 32), g3 = __shfl_xor(sd3, 32);
        union { unsigned u[4]; short8 v; } pu;
        pu.u[0] = useswap ? g0 : kp0;
        pu.u[1] = useswap ? g1 : kp1;
        pu.u[2] = useswap ? g2 : kp2;
        pu.u[3] = useswap ? g3 : kp3;
        pa[kk] = pu.v;
      }

      // O += P V (identical PV to verified R2, pf now from registers)
      __builtin_amdgcn_s_setprio(1);
#pragma unroll
      for (int kk = 0; kk < 2; ++kk) {
#pragma unroll
        for (int f = 0; f < 8; ++f) {
          int d = f * 16 + r16;
          short8 vf = *(const short8*)__builtin_assume_aligned(
              &Vsm[b][d * 64 + ((kk * 32 + kg * 8) ^ ((d & 7) << 3))], 16);
          o[f] = __builtin_amdgcn_mfma_f32_16x16x32_bf16(pa[kk], vf, o[f], 0, 0, 0);
        }
      }
      __builtin_amdgcn_s_setprio(0);
    }

    // epilogue: O[q = q0 + w*16 + kg*4 + j][d = f*16 + r16]
    float inv = 1.f / lrow;
    float invj[4];
#pragma unroll
    for (int j = 0; j < 4; ++j) invj[j] = __shfl(inv, kg * 4 + j);
#pragma unroll
    for (int j = 0; j < 4; ++j) {
      int row = q0 + w * 16 + kg * 4 + j;
      unsigned short* yr = Y + (size_t)row * 4096 + h * 128;
#pragma unroll
      for (int f = 0; f < 8; ++f) yr[f * 16 + r16] = f2bf(o[f][j] * invj[j]);
    }
  };

  const int pr = blockIdx.x;      // 0..15
  process(pr * 64);               // light tile
  process((31 - pr) * 64);        // heavy tile: total 33 KV-tiles per block
}

extern "C" void kernel_launch(void* const* d_in, const int* in_sizes, int n_in,
                              void* d_out, int out_size, void* d_ws, size_t ws_size,
                              hipStream_t stream) {
  const float* x      = (const float*)d_in[0];
  const float* cosb   = (const float*)d_in[1];
  const float* sinb   = (const float*)d_in[2];
  const float* w_attn = (const float*)d_in[3];
  const float* w_proj = (const float*)d_in[4];
  float* out = (float*)d_out;

  char* ws = (char*)d_ws;
  const size_t MB = 1024 * 1024;
  unsigned short* Xb  = (unsigned short*)(ws);
  unsigned short* Wa  = (unsigned short*)(ws + 16 * MB);
  unsigned short* Wp  = (unsigned short*)(ws);            // after gemm1
  unsigned short* Qb  = (unsigned short*)(ws + 32 * MB);  // after gemm1
  unsigned short* Kb  = (unsigned short*)(ws + 48 * MB);  // after gemm1
  unsigned short* Vt  = (unsigned short*)(ws + 52 * MB);  // after gemm1
  unsigned short* qkv = (unsigned short*)(ws + 64 * MB);
  unsigned short* Yb  = (unsigned short*)(ws + 64 * MB);  // after rope+transpose

  f32_to_bf16<<<4096, 256, 0, stream>>>(x, Xb, 2048 * 4096 / 8);
  f32_to_bf16<<<12288, 256, 0, stream>>>(w_attn, Wa, 6144 * 4096 / 8);
  gemm_bt_bf16<false><<<dim3(16, 48), 256, 0, stream>>>(Xb, Wa, qkv, 2048, 6144, 4096);
  rope_qk<<<20480, 256, 0, stream>>>(qkv, cosb, sinb, Qb, Kb);
  transpose_v<<<dim3(32, 8), 256, 0, stream>>>(qkv, Vt);
  f32_to_bf16<<<8192, 256, 0, stream>>>(w_proj, Wp, 4096 * 4096 / 8);
  flash_attn<<<dim3(16, 32), 256, 0, stream>>>(Qb, Kb, Vt, Yb);
  gemm_bt_bf16<true><<<dim3(16, 32), 256, 0, stream>>>(Yb, Wp, out, 2048, 4096, 4096);
}

// Round 5
// 341.167 us; speedup vs baseline: 1.2859x; 1.0306x over previous
//
#include <hip/hip_runtime.h>
#include <hip/hip_bf16.h>

typedef __attribute__((ext_vector_type(8))) short short8;
typedef __attribute__((ext_vector_type(4))) float f32x4;

__device__ inline unsigned short f2bf(float f) {
  __hip_bfloat16 h = __float2bfloat16(f);
  return *reinterpret_cast<unsigned short*>(&h);
}
__device__ inline float bf2f(unsigned short u) {
  union { unsigned u; float f; } v; v.u = ((unsigned)u) << 16;
  return v.f;
}

#define GLOAD_LDS16(g, l)                                          \
  __builtin_amdgcn_global_load_lds(                                \
      (const __attribute__((address_space(1))) void*)(g),          \
      (__attribute__((address_space(3))) void*)(l), 16, 0, 0)

// ---------------- f32 -> bf16 bulk convert (8 elems/thread) ----------------
__global__ void f32_to_bf16(const float* __restrict__ in,
                            unsigned short* __restrict__ out, int n8) {
  int i = blockIdx.x * 256 + threadIdx.x;
  if (i >= n8) return;
  const float4* p = (const float4*)in + (size_t)i * 2;
  float4 a = p[0], b = p[1];
  short8 v;
  v[0] = f2bf(a.x); v[1] = f2bf(a.y); v[2] = f2bf(a.z); v[3] = f2bf(a.w);
  v[4] = f2bf(b.x); v[5] = f2bf(b.y); v[6] = f2bf(b.z); v[7] = f2bf(b.w);
  *((short8*)out + i) = v;
}

// ======== 256-row 8-phase GEMM (T2+T3+T4+T5): C[M][N] = A[M][K]*B[N][K]^T ========
// BM=256, BK=64, 8 waves (2M x 4N). BN = 256 or 128. LDS: 2buf x (2 A-halves +
// BN/128 B-halves) x [128][64] bf16, chunk-XOR swizzled (involution, rule #21).
// 4 phases/K-tile, counted vmcnt (never 0 in steady state), raw s_barrier.
template <int BN, bool OUT_F32>
__global__ __launch_bounds__(512, 2)
void gemm256(const unsigned short* __restrict__ A, const unsigned short* __restrict__ B,
             void* __restrict__ Cp, int M, int N, int K, int nbm) {
  constexpr int BPARTS = BN / 128;     // B half-tiles (2 or 1)
  constexpr int WN = BN / 4;           // wave N-width (64 or 32)
  constexpr int NREP = WN / 16;        // N fragments per wave (4 or 2)
  constexpr int NQ = NREP / 2;         // N frags per quadrant (2 or 1)
  constexpr int LPK = 4 + 2 * BPARTS;  // gload_lds issues per K-tile per wave (8 or 6)

  __shared__ __align__(16) unsigned short lds[2][2 + BPARTS][128 * 64];

  const int t = threadIdx.x, lane = t & 63, w = t >> 6;
  const int wm = w >> 2, wn = w & 3;
  const int r16 = lane & 15, kg = lane >> 4;
  const int bid = blockIdx.x;
  const int bm = bid % nbm, bn = bid / nbm;
  const int NT = K >> 6;

  const int sr = lane >> 3, sch = lane & 7;  // staging: 8 rows x 8 chunks per issue
  const unsigned short* Ag = A + (size_t)(bm * 256) * K;
  const unsigned short* Bg = B + (size_t)(bn * BN) * K;

  // stage half h of A/B for K-tile kt into buf b: 2 gload_lds, pre-swizzled source
  auto stageA = [&](int kt, int h, int b) {
#pragma unroll
    for (int i = 0; i < 2; ++i) {
      int rb = w * 16 + i * 8;
      int rl = rb + sr;
      int sc = sch ^ (rl & 7);
      GLOAD_LDS16(Ag + (size_t)(h * 128 + rl) * K + kt * 64 + sc * 8,
                  &lds[b][h][rb * 64]);
    }
  };
  auto stageB = [&](int kt, int h, int b) {
#pragma unroll
    for (int i = 0; i < 2; ++i) {
      int rb = w * 16 + i * 8;
      int rl = rb + sr;
      int sc = sch ^ (rl & 7);
      GLOAD_LDS16(Bg + (size_t)(h * 128 + rl) * K + kt * 64 + sc * 8,
                  &lds[b][2 + h][rb * 64]);
    }
  };

  const int bpart = (wn * WN) >> 7;    // which B half this wave reads
  const int brow0 = (wn * WN) & 127;   // row base within that half

  auto lda = [&](int b, int m, int kk) -> short8 {
    int rp = m * 16 + r16;
    int ch = (kk * 4 + kg) ^ (rp & 7);
    return *(const short8*)__builtin_assume_aligned(&lds[b][wm][rp * 64 + ch * 8], 16);
  };
  auto ldb = [&](int b, int n, int kk) -> short8 {
    int rp = brow0 + n * 16 + r16;
    int ch = (kk * 4 + kg) ^ (rp & 7);
    return *(const short8*)__builtin_assume_aligned(&lds[b][2 + bpart][rp * 64 + ch * 8], 16);
  };

  f32x4 acc[8][NREP] = {};
  short8 a0[4][2], a1[4][2], bb[NREP][2];

#define MFMA_Q(AARR, MB, NB)                                                   \
  _Pragma("unroll") for (int m = 0; m < 4; ++m)                                \
  _Pragma("unroll") for (int n = 0; n < NQ; ++n)                               \
  _Pragma("unroll") for (int kk = 0; kk < 2; ++kk)                             \
      acc[MB + m][NB + n] = __builtin_amdgcn_mfma_f32_16x16x32_bf16(           \
          AARR[m][kk], bb[NB + n][kk], acc[MB + m][NB + n], 0, 0, 0);

#define LGKM0_FENCE()                                       \
  asm volatile("s_waitcnt lgkmcnt(0)" ::: "memory");        \
  __builtin_amdgcn_sched_barrier(0);

  // ---- prologue: stage K-tiles 0 and 1; wait for tile 0 ----
  stageB(0, 0, 0); if (BPARTS == 2) stageB(0, 1, 0);
  stageA(0, 0, 0); stageA(0, 1, 0);
  stageB(1, 0, 1); if (BPARTS == 2) stageB(1, 1, 1);
  stageA(1, 0, 1); stageA(1, 1, 1);
  asm volatile("s_waitcnt vmcnt(%0)" :: "n"(LPK) : "memory");
  __builtin_amdgcn_s_barrier();

  for (int kt = 0; kt < NT; ++kt) {
    const int b = kt & 1;
    const bool pf = (kt + 2) < NT;

    // ---- P1: ds_read A-lo + B[0..NQ); MFMA quad(0,0) ----
#pragma unroll
    for (int m = 0; m < 4; ++m) { a0[m][0] = lda(b, m, 0); a0[m][1] = lda(b, m, 1); }
#pragma unroll
    for (int n = 0; n < NQ; ++n) { bb[n][0] = ldb(b, n, 0); bb[n][1] = ldb(b, n, 1); }
    __builtin_amdgcn_s_barrier();
    LGKM0_FENCE();
    __builtin_amdgcn_s_setprio(1);
    MFMA_Q(a0, 0, 0);
    __builtin_amdgcn_s_setprio(0);
    __builtin_amdgcn_s_barrier();

    // ---- P2: ds_read B[NQ..NREP); MFMA quad(0,1) ----
#pragma unroll
    for (int n = 0; n < NQ; ++n) { bb[NQ + n][0] = ldb(b, NQ + n, 0); bb[NQ + n][1] = ldb(b, NQ + n, 1); }
    __builtin_amdgcn_s_barrier();
    LGKM0_FENCE();
    __builtin_amdgcn_s_setprio(1);
    MFMA_Q(a0, 0, NQ);
    __builtin_amdgcn_s_setprio(0);
    __builtin_amdgcn_s_barrier();

    // ---- P3: ds_read A-hi; stage kt+2 B-halves (B reads done @P2 barrier); MFMA quad(1,1)
#pragma unroll
    for (int m = 0; m < 4; ++m) { a1[m][0] = lda(b, 4 + m, 0); a1[m][1] = lda(b, 4 + m, 1); }
    if (pf) { stageB(kt + 2, 0, b); if (BPARTS == 2) stageB(kt + 2, 1, b); }
    __builtin_amdgcn_s_barrier();
    LGKM0_FENCE();
    __builtin_amdgcn_s_setprio(1);
    MFMA_Q(a1, 4, NQ);
    __builtin_amdgcn_s_setprio(0);
    __builtin_amdgcn_s_barrier();

    // ---- P4: stage kt+2 A-halves (A reads done @P3 barrier); MFMA quad(1,0) ----
    if (pf) { stageA(kt + 2, 0, b); stageA(kt + 2, 1, b); }
    __builtin_amdgcn_s_barrier();
    __builtin_amdgcn_s_setprio(1);
    MFMA_Q(a1, 4, 0);
    __builtin_amdgcn_s_setprio(0);
    if (kt + 1 < NT) {
      // drain kt+1's loads; kt+2's LPK stay in flight (counted, never 0 in steady state)
      if (pf) asm volatile("s_waitcnt vmcnt(%0)" :: "n"(LPK) : "memory");
      else    asm volatile("s_waitcnt vmcnt(0)" ::: "memory");
      __builtin_amdgcn_sched_barrier(0);
      __builtin_amdgcn_s_barrier();
    }
  }
#undef MFMA_Q
#undef LGKM0_FENCE

  // ---- epilogue ----
#pragma unroll
  for (int m = 0; m < 8; ++m) {
#pragma unroll
    for (int n = 0; n < NREP; ++n) {
#pragma unroll
      for (int j = 0; j < 4; ++j) {
        int row = bm * 256 + wm * 128 + m * 16 + kg * 4 + j;
        int col = bn * BN + wn * WN + n * 16 + r16;
        if (OUT_F32) ((float*)Cp)[(size_t)row * N + col] = acc[m][n][j];
        else ((unsigned short*)Cp)[(size_t)row * N + col] = f2bf(acc[m][n][j]);
      }
    }
  }
}

// ---------------- RoPE for Q (with 1/sqrt(hs)) and K; scatter ----------------
__global__ void rope_qk(const unsigned short* __restrict__ qkv,
                        const float* __restrict__ cosb, const float* __restrict__ sinb,
                        unsigned short* __restrict__ Q, unsigned short* __restrict__ K) {
  int pair = blockIdx.x * 4 + (threadIdx.x >> 6);
  int l = threadIdx.x & 63;
  int t = pair / 40, slot = pair - t * 40;
  const unsigned short* src;
  unsigned short* dst;
  float scale;
  if (slot < 32) {
    int g = slot >> 2, j = slot & 3;
    src = qkv + (size_t)t * 6144 + g * 768 + j * 128;
    dst = Q + ((size_t)slot * 2048 + t) * 128;
    scale = 0.08838834764831845f;  // 1/sqrt(128)
  } else {
    int g = slot - 32;
    src = qkv + (size_t)t * 6144 + g * 768 + 512;
    dst = K + ((size_t)g * 2048 + t) * 128;
    scale = 1.0f;
  }
  float x1 = bf2f(src[l]), x2 = bf2f(src[64 + l]);
  float c1 = cosb[t * 128 + l], s1 = sinb[t * 128 + l];
  float c2 = cosb[t * 128 + 64 + l], s2 = sinb[t * 128 + 64 + l];
  dst[l]      = f2bf((x1 * c1 - x2 * s1) * scale);
  dst[64 + l] = f2bf((x2 * c2 + x1 * s2) * scale);
}

// ---------------- Vt[g][d][t] = qkv[t][g*768+640+d] ----------------
__global__ void transpose_v(const unsigned short* __restrict__ qkv,
                            unsigned short* __restrict__ Vt) {
  __shared__ __align__(16) unsigned short tile[64][136];
  int g = blockIdx.y, t0 = blockIdx.x * 64;
  int th = threadIdx.x;
  int r = th >> 2, c0 = (th & 3) * 32;
  const unsigned short* src = qkv + (size_t)(t0 + r) * 6144 + g * 768 + 640 + c0;
#pragma unroll
  for (int i = 0; i < 4; ++i)
    *(short8*)&tile[r][c0 + i * 8] = *(const short8*)(src + i * 8);
  __syncthreads();
  int d = th >> 1, tc = (th & 1) * 32;
  unsigned short* dst = Vt + (size_t)(g * 128 + d) * 2048 + t0 + tc;
#pragma unroll
  for (int j = 0; j < 32; ++j) dst[j] = tile[tc + j][d];
}

// ---------------- Flash attention v3: swapped QK^T, in-register softmax ----------------
__global__ __launch_bounds__(256, 2)
void flash_attn(const unsigned short* __restrict__ Q, const unsigned short* __restrict__ K,
                const unsigned short* __restrict__ Vt, unsigned short* __restrict__ Y) {
  __shared__ __align__(16) unsigned short Ksm[2][64 * 128];   // [kv][d], XOR-swizzled
  __shared__ __align__(16) unsigned short Vsm[2][128 * 64];   // [d][kv], XOR-swizzled

  const int h = blockIdx.y, g = h >> 2;
  const int t = threadIdx.x, lane = t & 63, w = t >> 6;
  const int r16 = lane & 15, kg = lane >> 4;
  const bool odd = kg & 1;
  const bool hi = kg >> 1;
  const bool useswap = odd ^ hi;

  const unsigned short* Kg = K + (size_t)g * 2048 * 128;
  const unsigned short* Vg = Vt + (size_t)g * 128 * 2048;

  const int krl = lane >> 4, kc = lane & 15;
  const int vrl = lane >> 3, vc = lane & 7;

  auto stage = [&](int kvs, int b) {
#pragma unroll
    for (int i = 0; i < 4; ++i) {
      int row = w * 16 + i * 4 + krl;
      int sc = kc ^ (row & 7);
      GLOAD_LDS16(Kg + (size_t)(kvs + row) * 128 + sc * 8,
                  &Ksm[b][(w * 16 + i * 4) * 128]);
    }
#pragma unroll
    for (int i = 0; i < 4; ++i) {
      int d = w * 32 + i * 8 + vrl;
      int sc = vc ^ (d & 7);
      GLOAD_LDS16(Vg + (size_t)d * 2048 + kvs + sc * 8,
                  &Vsm[b][(w * 32 + i * 8) * 64]);
    }
  };

  auto process = [&](int q0) {
    short8 qf[4];
    const unsigned short* qrow = Q + ((size_t)h * 2048 + q0 + w * 16 + r16) * 128;
#pragma unroll
    for (int kk = 0; kk < 4; ++kk) qf[kk] = *(const short8*)(qrow + kk * 32 + kg * 8);

    f32x4 o[8] = {};
    float mrow = -1e30f, lrow = 0.f;
    const int qg = q0 + w * 16 + r16;
    const int nt = q0 / 64 + 1;

    __syncthreads();
    stage(0, 0);

    for (int kt = 0; kt < nt; ++kt) {
      const int b = kt & 1;
      const int kv0 = kt * 64;
      __syncthreads();
      if (kt + 1 < nt) stage((kt + 1) * 64, b ^ 1);

      f32x4 s[4] = {};
      __builtin_amdgcn_s_setprio(1);
#pragma unroll
      for (int n = 0; n < 4; ++n) {
        int kr = n * 16 + r16;
#pragma unroll
        for (int kk = 0; kk < 4; ++kk) {
          short8 kf = *(const short8*)__builtin_assume_aligned(
              &Ksm[b][kr * 128 + ((kk * 32 + kg * 8) ^ ((kr & 7) << 3))], 16);
          s[n] = __builtin_amdgcn_mfma_f32_16x16x32_bf16(kf, qf[kk], s[n], 0, 0, 0);
        }
      }
      __builtin_amdgcn_s_setprio(0);

      if (kv0 + 63 > q0 + w * 16) {
#pragma unroll
        for (int n = 0; n < 4; ++n)
#pragma unroll
          for (int j = 0; j < 4; ++j)
            if (kv0 + n * 16 + kg * 4 + j > qg) s[n][j] = -1e30f;
      }

      float rmax = -1e30f;
#pragma unroll
      for (int n = 0; n < 4; ++n)
#pragma unroll
        for (int j = 0; j < 4; ++j) rmax = fmaxf(rmax, s[n][j]);
      rmax = fmaxf(rmax, __shfl_xor(rmax, 16));
      rmax = fmaxf(rmax, __shfl_xor(rmax, 32));

      if (__builtin_amdgcn_ballot_w64(rmax > mrow)) {
        float mnew = fmaxf(mrow, rmax);
        float fac = __expf(mrow - mnew);
        mrow = mnew;
        lrow *= fac;
        float fj[4];
#pragma unroll
        for (int j = 0; j < 4; ++j) fj[j] = __shfl(fac, kg * 4 + j);
#pragma unroll
        for (int f = 0; f < 8; ++f)
#pragma unroll
          for (int j = 0; j < 4; ++j) o[f][j] *= fj[j];
      }

      float p[4][4];
      float rs = 0.f;
#pragma unroll
      for (int n = 0; n < 4; ++n)
#pragma unroll
        for (int j = 0; j < 4; ++j) {
          p[n][j] = __expf(s[n][j] - mrow);
          rs += p[n][j];
        }
      rs += __shfl_xor(rs, 16);
      rs += __shfl_xor(rs, 32);
      lrow += rs;

      unsigned bpk[4][2], xpk[4][2];
#pragma unroll
      for (int n = 0; n < 4; ++n)
#pragma unroll
        for (int i = 0; i < 2; ++i)
          bpk[n][i] = (unsigned)f2bf(p[n][2 * i]) | ((unsigned)f2bf(p[n][2 * i + 1]) << 16);
#pragma unroll
      for (int n = 0; n < 4; ++n)
#pragma unroll
        for (int i = 0; i < 2; ++i) xpk[n][i] = __shfl_xor(bpk[n][i], 16);

      unsigned pl[4][2], ph[4][2];
#pragma unroll
      for (int n = 0; n < 4; ++n)
#pragma unroll
        for (int i = 0; i < 2; ++i) {
          pl[n][i] = odd ? xpk[n][i] : bpk[n][i];
          ph[n][i] = odd ? bpk[n][i] : xpk[n][i];
        }

      short8 pa[2];
#pragma unroll
      for (int kk = 0; kk < 2; ++kk) {
        unsigned kp0 = hi ? pl[2 * kk + 1][0] : pl[2 * kk][0];
        unsigned kp1 = hi ? pl[2 * kk + 1][1] : pl[2 * kk][1];
        unsigned kp2 = hi ? ph[2 * kk + 1][0] : ph[2 * kk][0];
        unsigned kp3 = hi ? ph[2 * kk + 1][1] : ph[2 * kk][1];
        unsigned sd0 = hi ? pl[2 * kk][0] : pl[2 * kk + 1][0];
        unsigned sd1 = hi ? pl[2 * kk][1] : pl[2 * kk + 1][1];
        unsigned sd2 = hi ? ph[2 * kk][0] : ph[2 * kk + 1][0];
        unsigned sd3 = hi ? ph[2 * kk][1] : ph[2 * kk + 1][1];
        unsigned g0 = __shfl_xor(sd0, 32), g1 = __shfl_xor(sd1, 32);
        unsigned g2 = __shfl_xor(sd2, 32), g3 = __shfl_xor(sd3, 32);
        union { unsigned u[4]; short8 v; } pu;
        pu.u[0] = useswap ? g0 : kp0;
        pu.u[1] = useswap ? g1 : kp1;
        pu.u[2] = useswap ? g2 : kp2;
        pu.u[3] = useswap ? g3 : kp3;
        pa[kk] = pu.v;
      }

      __builtin_amdgcn_s_setprio(1);
#pragma unroll
      for (int kk = 0; kk < 2; ++kk) {
#pragma unroll
        for (int f = 0; f < 8; ++f) {
          int d = f * 16 + r16;
          short8 vf = *(const short8*)__builtin_assume_aligned(
              &Vsm[b][d * 64 + ((kk * 32 + kg * 8) ^ ((d & 7) << 3))], 16);
          o[f] = __builtin_amdgcn_mfma_f32_16x16x32_bf16(pa[kk], vf, o[f], 0, 0, 0);
        }
      }
      __builtin_amdgcn_s_setprio(0);
    }

    float inv = 1.f / lrow;
    float invj[4];
#pragma unroll
    for (int j = 0; j < 4; ++j) invj[j] = __shfl(inv, kg * 4 + j);
#pragma unroll
    for (int j = 0; j < 4; ++j) {
      int row = q0 + w * 16 + kg * 4 + j;
      unsigned short* yr = Y + (size_t)row * 4096 + h * 128;
#pragma unroll
      for (int f = 0; f < 8; ++f) yr[f * 16 + r16] = f2bf(o[f][j] * invj[j]);
    }
  };

  const int pr = blockIdx.x;
  process(pr * 64);
  process((31 - pr) * 64);
}

extern "C" void kernel_launch(void* const* d_in, const int* in_sizes, int n_in,
                              void* d_out, int out_size, void* d_ws, size_t ws_size,
                              hipStream_t stream) {
  const float* x      = (const float*)d_in[0];
  const float* cosb   = (const float*)d_in[1];
  const float* sinb   = (const float*)d_in[2];
  const float* w_attn = (const float*)d_in[3];
  const float* w_proj = (const float*)d_in[4];
  float* out = (float*)d_out;

  char* ws = (char*)d_ws;
  const size_t MB = 1024 * 1024;
  unsigned short* Xb  = (unsigned short*)(ws);
  unsigned short* Wa  = (unsigned short*)(ws + 16 * MB);
  unsigned short* Wp  = (unsigned short*)(ws);            // after gemm1
  unsigned short* Qb  = (unsigned short*)(ws + 32 * MB);  // after gemm1
  unsigned short* Kb  = (unsigned short*)(ws + 48 * MB);  // after gemm1
  unsigned short* Vt  = (unsigned short*)(ws + 52 * MB);  // after gemm1
  unsigned short* qkv = (unsigned short*)(ws + 64 * MB);
  unsigned short* Yb  = (unsigned short*)(ws + 64 * MB);  // after rope+transpose

  f32_to_bf16<<<4096, 256, 0, stream>>>(x, Xb, 2048 * 4096 / 8);
  f32_to_bf16<<<12288, 256, 0, stream>>>(w_attn, Wa, 6144 * 4096 / 8);
  gemm256<256, false><<<192, 512, 0, stream>>>(Xb, Wa, qkv, 2048, 6144, 4096, 8);
  rope_qk<<<20480, 256, 0, stream>>>(qkv, cosb, sinb, Qb, Kb);
  transpose_v<<<dim3(32, 8), 256, 0, stream>>>(qkv, Vt);
  f32_to_bf16<<<8192, 256, 0, stream>>>(w_proj, Wp, 4096 * 4096 / 8);
  flash_attn<<<dim3(16, 32), 256, 0, stream>>>(Qb, Kb, Vt, Yb);
  gemm256<128, true><<<256, 512, 0, stream>>>(Yb, Wp, out, 2048, 4096, 4096, 8);
}

// Round 6
// 315.509 us; speedup vs baseline: 1.3905x; 1.0813x over previous
//
#include <hip/hip_runtime.h>
#include <hip/hip_bf16.h>

typedef __attribute__((ext_vector_type(8))) short short8;
typedef __attribute__((ext_vector_type(4))) float f32x4;

__device__ inline unsigned short f2bf(float f) {
  __hip_bfloat16 h = __float2bfloat16(f);
  return *reinterpret_cast<unsigned short*>(&h);
}
__device__ inline float bf2f(unsigned short u) {
  union { unsigned u; float f; } v; v.u = ((unsigned)u) << 16;
  return v.f;
}

#define GLOAD_LDS16(g, l)                                          \
  __builtin_amdgcn_global_load_lds(                                \
      (const __attribute__((address_space(1))) void*)(g),          \
      (__attribute__((address_space(3))) void*)(l), 16, 0, 0)

#define MFMA16(a, b, c) __builtin_amdgcn_mfma_f32_16x16x32_bf16((a), (b), (c), 0, 0, 0)

#define LGKM0()                                              \
  asm volatile("s_waitcnt lgkmcnt(0)" ::: "memory");         \
  __builtin_amdgcn_sched_barrier(0);

// ---------------- f32 -> bf16 bulk convert (8 elems/thread) ----------------
__global__ void f32_to_bf16(const float* __restrict__ in,
                            unsigned short* __restrict__ out, int n8) {
  int i = blockIdx.x * 256 + threadIdx.x;
  if (i >= n8) return;
  const float4* p = (const float4*)in + (size_t)i * 2;
  float4 a = p[0], b = p[1];
  short8 v;
  v[0] = f2bf(a.x); v[1] = f2bf(a.y); v[2] = f2bf(a.z); v[3] = f2bf(a.w);
  v[4] = f2bf(b.x); v[5] = f2bf(b.y); v[6] = f2bf(b.z); v[7] = f2bf(b.w);
  *((short8*)out + i) = v;
}

// ======== GEMM1: BM=256 x BN=192, grid 8x32=256, 3 phases/K-tile ========
// C[M][N] = A[M][K]*B[N][K]^T, bf16 out. 8 waves (2M x 4N), wave tile 128x48.
__global__ __launch_bounds__(512, 2)
void gemm_qkv(const unsigned short* __restrict__ A, const unsigned short* __restrict__ B,
              unsigned short* __restrict__ C, int M, int N, int K) {
  __shared__ __align__(16) unsigned short lds[2][448 * 64];  // A rows 0..255, B rows 256..447
  const int t = threadIdx.x, lane = t & 63, w = t >> 6;
  const int wm = w >> 2, wn = w & 3;
  const int r16 = lane & 15, kg = lane >> 4;
  const int bm = blockIdx.x & 7, bn = blockIdx.x >> 3;  // XCD = bid%8 = bm: A panel L2-resident
  const int NT = K >> 6;
  const int sr = lane >> 3, sch = lane & 7;
  const unsigned short* Ag = A + (size_t)(bm * 256) * K;
  const unsigned short* Bg = B + (size_t)(bn * 192) * K;

  auto stA = [&](int kt, int j, int b) {
    int rl = j * 64 + w * 8 + sr, sc = sch ^ (rl & 7);
    GLOAD_LDS16(Ag + (size_t)rl * K + kt * 64 + sc * 8, &lds[b][(j * 64 + w * 8) * 64]);
  };
  auto stB = [&](int kt, int j, int b) {
    int rl = j * 64 + w * 8 + sr, sc = sch ^ (rl & 7);
    GLOAD_LDS16(Bg + (size_t)rl * K + kt * 64 + sc * 8, &lds[b][(256 + j * 64 + w * 8) * 64]);
  };
  auto lda = [&](int b, int m, int kk) -> short8 {
    int row = wm * 128 + m * 16 + r16, ch = (kk * 4 + kg) ^ (row & 7);
    return *(const short8*)__builtin_assume_aligned(&lds[b][row * 64 + ch * 8], 16);
  };
  auto ldb = [&](int b, int n, int kk) -> short8 {
    int row = wn * 48 + n * 16 + r16, ch = (kk * 4 + kg) ^ (row & 7);
    return *(const short8*)__builtin_assume_aligned(&lds[b][(256 + row) * 64 + ch * 8], 16);
  };

  f32x4 acc[8][3] = {};
  short8 a0[4][2], a1[4][2], bb[3][2];

  // prologue: tile0 full (7 issues), tile1 all but A3 (6); spill A3 in t0's P1
#pragma unroll
  for (int j = 0; j < 4; ++j) stA(0, j, 0);
#pragma unroll
  for (int j = 0; j < 3; ++j) stB(0, j, 0);
#pragma unroll
  for (int j = 0; j < 3; ++j) stA(1, j, 1);
#pragma unroll
  for (int j = 0; j < 3; ++j) stB(1, j, 1);
  asm volatile("s_waitcnt vmcnt(6)" ::: "memory");
  __builtin_amdgcn_sched_barrier(0);
  __builtin_amdgcn_s_barrier();

  for (int kt = 0; kt < NT; ++kt) {
    const int b = kt & 1;
    const bool pf1 = kt + 1 < NT, pf2 = kt + 2 < NT;

    // ---- P1: spill-stage A3(t+1); read a0(8)+b01(4); MFMA m0-3 x n0-1 ----
    if (pf1) stA(kt + 1, 3, b ^ 1);  // region freed at t-1's P2-end
#pragma unroll
    for (int m = 0; m < 4; ++m) { a0[m][0] = lda(b, m, 0); a0[m][1] = lda(b, m, 1); }
#pragma unroll
    for (int n = 0; n < 2; ++n) { bb[n][0] = ldb(b, n, 0); bb[n][1] = ldb(b, n, 1); }
    __builtin_amdgcn_s_barrier();
    LGKM0();
    __builtin_amdgcn_s_setprio(1);
#pragma unroll
    for (int m = 0; m < 4; ++m)
#pragma unroll
      for (int n = 0; n < 2; ++n)
#pragma unroll
        for (int kk = 0; kk < 2; ++kk) acc[m][n] = MFMA16(a0[m][kk], bb[n][kk], acc[m][n]);
    __builtin_amdgcn_s_setprio(0);
    __builtin_amdgcn_s_barrier();

    // ---- P2: read b2(2)+a1(8); stage A0,A2(t+2) (freed end-P1); MFMA (m0-7) x n2 ----
    bb[2][0] = ldb(b, 2, 0); bb[2][1] = ldb(b, 2, 1);
#pragma unroll
    for (int m = 0; m < 4; ++m) { a1[m][0] = lda(b, 4 + m, 0); a1[m][1] = lda(b, 4 + m, 1); }
    if (pf2) { stA(kt + 2, 0, b); stA(kt + 2, 2, b); }
    __builtin_amdgcn_s_barrier();
    LGKM0();
    __builtin_amdgcn_s_setprio(1);
#pragma unroll
    for (int m = 0; m < 4; ++m)
#pragma unroll
      for (int kk = 0; kk < 2; ++kk) acc[m][2] = MFMA16(a0[m][kk], bb[2][kk], acc[m][2]);
#pragma unroll
    for (int m = 0; m < 4; ++m)
#pragma unroll
      for (int kk = 0; kk < 2; ++kk) acc[4 + m][2] = MFMA16(a1[m][kk], bb[2][kk], acc[4 + m][2]);
    __builtin_amdgcn_s_setprio(0);
    __builtin_amdgcn_s_barrier();

    // ---- P3: stage B0,B1,B2,A1(t+2) (B freed end-P2, A1 freed end-P2); MFMA m4-7 x n0-1 ----
    if (pf2) { stB(kt + 2, 0, b); stB(kt + 2, 1, b); stB(kt + 2, 2, b); stA(kt + 2, 1, b); }
    __builtin_amdgcn_s_barrier();
    __builtin_amdgcn_s_setprio(1);
#pragma unroll
    for (int m = 0; m < 4; ++m)
#pragma unroll
      for (int n = 0; n < 2; ++n)
#pragma unroll
        for (int kk = 0; kk < 2; ++kk) acc[4 + m][n] = MFMA16(a1[m][kk], bb[n][kk], acc[4 + m][n]);
    __builtin_amdgcn_s_setprio(0);
    if (pf1) {  // drain t+1 (7 issues); keep t+2's 6 in flight
      if (pf2) asm volatile("s_waitcnt vmcnt(6)" ::: "memory");
      else     asm volatile("s_waitcnt vmcnt(0)" ::: "memory");
      __builtin_amdgcn_sched_barrier(0);
      __builtin_amdgcn_s_barrier();
    }
  }

#pragma unroll
  for (int m = 0; m < 8; ++m)
#pragma unroll
    for (int n = 0; n < 3; ++n)
#pragma unroll
      for (int j = 0; j < 4; ++j) {
        int row = bm * 256 + wm * 128 + m * 16 + kg * 4 + j;
        int col = bn * 192 + wn * 48 + n * 16 + r16;
        C[(size_t)row * N + col] = f2bf(acc[m][n][j]);
      }
}

// ======== GEMM2: BM=128 x BN=256, grid 16x16=256, 2 phases/K-tile, f32 out ========
__global__ __launch_bounds__(512, 2)
void gemm_proj(const unsigned short* __restrict__ A, const unsigned short* __restrict__ B,
               float* __restrict__ C, int M, int N, int K) {
  __shared__ __align__(16) unsigned short lds[2][384 * 64];  // A rows 0..127, B rows 128..383
  const int t = threadIdx.x, lane = t & 63, w = t >> 6;
  const int wm = w >> 2, wn = w & 3;
  const int r16 = lane & 15, kg = lane >> 4;
  const int bm = blockIdx.x & 15, bn = blockIdx.x >> 4;
  const int NT = K >> 6;
  const int sr = lane >> 3, sch = lane & 7;
  const unsigned short* Ag = A + (size_t)(bm * 128) * K;
  const unsigned short* Bg = B + (size_t)(bn * 256) * K;

  auto stA = [&](int kt, int j, int b) {
    int rl = j * 64 + w * 8 + sr, sc = sch ^ (rl & 7);
    GLOAD_LDS16(Ag + (size_t)rl * K + kt * 64 + sc * 8, &lds[b][(j * 64 + w * 8) * 64]);
  };
  auto stB = [&](int kt, int j, int b) {
    int rl = j * 64 + w * 8 + sr, sc = sch ^ (rl & 7);
    GLOAD_LDS16(Bg + (size_t)rl * K + kt * 64 + sc * 8, &lds[b][(128 + j * 64 + w * 8) * 64]);
  };
  auto lda = [&](int b, int m, int kk) -> short8 {
    int row = wm * 64 + m * 16 + r16, ch = (kk * 4 + kg) ^ (row & 7);
    return *(const short8*)__builtin_assume_aligned(&lds[b][row * 64 + ch * 8], 16);
  };
  auto ldb = [&](int b, int n, int kk) -> short8 {
    int row = wn * 64 + n * 16 + r16, ch = (kk * 4 + kg) ^ (row & 7);
    return *(const short8*)__builtin_assume_aligned(&lds[b][(128 + row) * 64 + ch * 8], 16);
  };

  f32x4 acc[4][4] = {};
  short8 af[4][2], bb[4][2];

  // prologue: tile0 full (6), tile1 A only (2); spill tile1's B (4) in t0's P1
#pragma unroll
  for (int j = 0; j < 2; ++j) stA(0, j, 0);
#pragma unroll
  for (int j = 0; j < 4; ++j) stB(0, j, 0);
#pragma unroll
  for (int j = 0; j < 2; ++j) stA(1, j, 1);
  asm volatile("s_waitcnt vmcnt(2)" ::: "memory");
  __builtin_amdgcn_sched_barrier(0);
  __builtin_amdgcn_s_barrier();

  for (int kt = 0; kt < NT; ++kt) {
    const int b = kt & 1;
    const bool pf1 = kt + 1 < NT, pf2 = kt + 2 < NT;

    // ---- P1: spill-stage B0-3(t+1) (freed at t-1 P2-end); read a(8)+b01(4); MFMA m x n0-1
    if (pf1) { stB(kt + 1, 0, b ^ 1); stB(kt + 1, 1, b ^ 1); stB(kt + 1, 2, b ^ 1); stB(kt + 1, 3, b ^ 1); }
#pragma unroll
    for (int m = 0; m < 4; ++m) { af[m][0] = lda(b, m, 0); af[m][1] = lda(b, m, 1); }
#pragma unroll
    for (int n = 0; n < 2; ++n) { bb[n][0] = ldb(b, n, 0); bb[n][1] = ldb(b, n, 1); }
    __builtin_amdgcn_s_barrier();
    LGKM0();
    __builtin_amdgcn_s_setprio(1);
#pragma unroll
    for (int m = 0; m < 4; ++m)
#pragma unroll
      for (int n = 0; n < 2; ++n)
#pragma unroll
        for (int kk = 0; kk < 2; ++kk) acc[m][n] = MFMA16(af[m][kk], bb[n][kk], acc[m][n]);
    __builtin_amdgcn_s_setprio(0);
    __builtin_amdgcn_s_barrier();

    // ---- P2: read b23(4); stage A0,A1(t+2) (A freed end-P1); MFMA m x n2-3 ----
#pragma unroll
    for (int n = 2; n < 4; ++n) { bb[n][0] = ldb(b, n, 0); bb[n][1] = ldb(b, n, 1); }
    if (pf2) { stA(kt + 2, 0, b); stA(kt + 2, 1, b); }
    __builtin_amdgcn_s_barrier();
    LGKM0();
    __builtin_amdgcn_s_setprio(1);
#pragma unroll
    for (int m = 0; m < 4; ++m)
#pragma unroll
      for (int n = 2; n < 4; ++n)
#pragma unroll
        for (int kk = 0; kk < 2; ++kk) acc[m][n] = MFMA16(af[m][kk], bb[n][kk], acc[m][n]);
    __builtin_amdgcn_s_setprio(0);
    if (pf1) {  // drain t+1 (6); keep t+2's 2 in flight
      if (pf2) asm volatile("s_waitcnt vmcnt(2)" ::: "memory");
      else     asm volatile("s_waitcnt vmcnt(0)" ::: "memory");
      __builtin_amdgcn_sched_barrier(0);
      __builtin_amdgcn_s_barrier();
    }
  }

#pragma unroll
  for (int m = 0; m < 4; ++m)
#pragma unroll
    for (int n = 0; n < 4; ++n)
#pragma unroll
      for (int j = 0; j < 4; ++j) {
        int row = bm * 128 + wm * 64 + m * 16 + kg * 4 + j;
        int col = bn * 256 + wn * 64 + n * 16 + r16;
        C[(size_t)row * N + col] = acc[m][n][j];
      }
}

// ---------------- RoPE for Q (with 1/sqrt(hs)) and K; scatter ----------------
__global__ void rope_qk(const unsigned short* __restrict__ qkv,
                        const float* __restrict__ cosb, const float* __restrict__ sinb,
                        unsigned short* __restrict__ Q, unsigned short* __restrict__ K) {
  int pair = blockIdx.x * 4 + (threadIdx.x >> 6);
  int l = threadIdx.x & 63;
  int t = pair / 40, slot = pair - t * 40;
  const unsigned short* src;
  unsigned short* dst;
  float scale;
  if (slot < 32) {
    int g = slot >> 2, j = slot & 3;
    src = qkv + (size_t)t * 6144 + g * 768 + j * 128;
    dst = Q + ((size_t)slot * 2048 + t) * 128;
    scale = 0.08838834764831845f;  // 1/sqrt(128)
  } else {
    int g = slot - 32;
    src = qkv + (size_t)t * 6144 + g * 768 + 512;
    dst = K + ((size_t)g * 2048 + t) * 128;
    scale = 1.0f;
  }
  float x1 = bf2f(src[l]), x2 = bf2f(src[64 + l]);
  float c1 = cosb[t * 128 + l], s1 = sinb[t * 128 + l];
  float c2 = cosb[t * 128 + 64 + l], s2 = sinb[t * 128 + 64 + l];
  dst[l]      = f2bf((x1 * c1 - x2 * s1) * scale);
  dst[64 + l] = f2bf((x2 * c2 + x1 * s2) * scale);
}

// ---------------- Vt[g][d][t] = qkv[t][g*768+640+d] ----------------
__global__ void transpose_v(const unsigned short* __restrict__ qkv,
                            unsigned short* __restrict__ Vt) {
  __shared__ __align__(16) unsigned short tile[64][136];
  int g = blockIdx.y, t0 = blockIdx.x * 64;
  int th = threadIdx.x;
  int r = th >> 2, c0 = (th & 3) * 32;
  const unsigned short* src = qkv + (size_t)(t0 + r) * 6144 + g * 768 + 640 + c0;
#pragma unroll
  for (int i = 0; i < 4; ++i)
    *(short8*)&tile[r][c0 + i * 8] = *(const short8*)(src + i * 8);
  __syncthreads();
  int d = th >> 1, tc = (th & 1) * 32;
  unsigned short* dst = Vt + (size_t)(g * 128 + d) * 2048 + t0 + tc;
#pragma unroll
  for (int j = 0; j < 32; ++j) dst[j] = tile[tc + j][d];
}

// ---------------- Flash attention v3: swapped QK^T, in-register softmax ----------------
__global__ __launch_bounds__(256, 2)
void flash_attn(const unsigned short* __restrict__ Q, const unsigned short* __restrict__ K,
                const unsigned short* __restrict__ Vt, unsigned short* __restrict__ Y) {
  __shared__ __align__(16) unsigned short Ksm[2][64 * 128];   // [kv][d], XOR-swizzled
  __shared__ __align__(16) unsigned short Vsm[2][128 * 64];   // [d][kv], XOR-swizzled

  const int h = blockIdx.y, g = h >> 2;
  const int t = threadIdx.x, lane = t & 63, w = t >> 6;
  const int r16 = lane & 15, kg = lane >> 4;
  const bool odd = kg & 1;
  const bool hi = kg >> 1;
  const bool useswap = odd ^ hi;

  const unsigned short* Kg = K + (size_t)g * 2048 * 128;
  const unsigned short* Vg = Vt + (size_t)g * 128 * 2048;

  const int krl = lane >> 4, kc = lane & 15;
  const int vrl = lane >> 3, vc = lane & 7;

  auto stage = [&](int kvs, int b) {
#pragma unroll
    for (int i = 0; i < 4; ++i) {
      int row = w * 16 + i * 4 + krl;
      int sc = kc ^ (row & 7);
      GLOAD_LDS16(Kg + (size_t)(kvs + row) * 128 + sc * 8,
                  &Ksm[b][(w * 16 + i * 4) * 128]);
    }
#pragma unroll
    for (int i = 0; i < 4; ++i) {
      int d = w * 32 + i * 8 + vrl;
      int sc = vc ^ (d & 7);
      GLOAD_LDS16(Vg + (size_t)d * 2048 + kvs + sc * 8,
                  &Vsm[b][(w * 32 + i * 8) * 64]);
    }
  };

  auto process = [&](int q0) {
    short8 qf[4];
    const unsigned short* qrow = Q + ((size_t)h * 2048 + q0 + w * 16 + r16) * 128;
#pragma unroll
    for (int kk = 0; kk < 4; ++kk) qf[kk] = *(const short8*)(qrow + kk * 32 + kg * 8);

    f32x4 o[8] = {};
    float mrow = -1e30f, lrow = 0.f;
    const int qg = q0 + w * 16 + r16;
    const int nt = q0 / 64 + 1;

    __syncthreads();
    stage(0, 0);

    for (int kt = 0; kt < nt; ++kt) {
      const int b = kt & 1;
      const int kv0 = kt * 64;
      __syncthreads();
      if (kt + 1 < nt) stage((kt + 1) * 64, b ^ 1);

      f32x4 s[4] = {};
      __builtin_amdgcn_s_setprio(1);
#pragma unroll
      for (int n = 0; n < 4; ++n) {
        int kr = n * 16 + r16;
#pragma unroll
        for (int kk = 0; kk < 4; ++kk) {
          short8 kf = *(const short8*)__builtin_assume_aligned(
              &Ksm[b][kr * 128 + ((kk * 32 + kg * 8) ^ ((kr & 7) << 3))], 16);
          s[n] = __builtin_amdgcn_mfma_f32_16x16x32_bf16(kf, qf[kk], s[n], 0, 0, 0);
        }
      }
      __builtin_amdgcn_s_setprio(0);

      if (kv0 + 63 > q0 + w * 16) {
#pragma unroll
        for (int n = 0; n < 4; ++n)
#pragma unroll
          for (int j = 0; j < 4; ++j)
            if (kv0 + n * 16 + kg * 4 + j > qg) s[n][j] = -1e30f;
      }

      float rmax = -1e30f;
#pragma unroll
      for (int n = 0; n < 4; ++n)
#pragma unroll
        for (int j = 0; j < 4; ++j) rmax = fmaxf(rmax, s[n][j]);
      rmax = fmaxf(rmax, __shfl_xor(rmax, 16));
      rmax = fmaxf(rmax, __shfl_xor(rmax, 32));

      if (__builtin_amdgcn_ballot_w64(rmax > mrow)) {
        float mnew = fmaxf(mrow, rmax);
        float fac = __expf(mrow - mnew);
        mrow = mnew;
        lrow *= fac;
        float fj[4];
#pragma unroll
        for (int j = 0; j < 4; ++j) fj[j] = __shfl(fac, kg * 4 + j);
#pragma unroll
        for (int f = 0; f < 8; ++f)
#pragma unroll
          for (int j = 0; j < 4; ++j) o[f][j] *= fj[j];
      }

      float p[4][4];
      float rs = 0.f;
#pragma unroll
      for (int n = 0; n < 4; ++n)
#pragma unroll
        for (int j = 0; j < 4; ++j) {
          p[n][j] = __expf(s[n][j] - mrow);
          rs += p[n][j];
        }
      rs += __shfl_xor(rs, 16);
      rs += __shfl_xor(rs, 32);
      lrow += rs;

      unsigned bpk[4][2], xpk[4][2];
#pragma unroll
      for (int n = 0; n < 4; ++n)
#pragma unroll
        for (int i = 0; i < 2; ++i)
          bpk[n][i] = (unsigned)f2bf(p[n][2 * i]) | ((unsigned)f2bf(p[n][2 * i + 1]) << 16);
#pragma unroll
      for (int n = 0; n < 4; ++n)
#pragma unroll
        for (int i = 0; i < 2; ++i) xpk[n][i] = __shfl_xor(bpk[n][i], 16);

      unsigned pl[4][2], ph[4][2];
#pragma unroll
      for (int n = 0; n < 4; ++n)
#pragma unroll
        for (int i = 0; i < 2; ++i) {
          pl[n][i] = odd ? xpk[n][i] : bpk[n][i];
          ph[n][i] = odd ? bpk[n][i] : xpk[n][i];
        }

      short8 pa[2];
#pragma unroll
      for (int kk = 0; kk < 2; ++kk) {
        unsigned kp0 = hi ? pl[2 * kk + 1][0] : pl[2 * kk][0];
        unsigned kp1 = hi ? pl[2 * kk + 1][1] : pl[2 * kk][1];
        unsigned kp2 = hi ? ph[2 * kk + 1][0] : ph[2 * kk][0];
        unsigned kp3 = hi ? ph[2 * kk + 1][1] : ph[2 * kk][1];
        unsigned sd0 = hi ? pl[2 * kk][0] : pl[2 * kk + 1][0];
        unsigned sd1 = hi ? pl[2 * kk][1] : pl[2 * kk + 1][1];
        unsigned sd2 = hi ? ph[2 * kk][0] : ph[2 * kk + 1][0];
        unsigned sd3 = hi ? ph[2 * kk][1] : ph[2 * kk + 1][1];
        unsigned g0 = __shfl_xor(sd0, 32), g1 = __shfl_xor(sd1, 32);
        unsigned g2 = __shfl_xor(sd2, 32), g3 = __shfl_xor(sd3, 32);
        union { unsigned u[4]; short8 v; } pu;
        pu.u[0] = useswap ? g0 : kp0;
        pu.u[1] = useswap ? g1 : kp1;
        pu.u[2] = useswap ? g2 : kp2;
        pu.u[3] = useswap ? g3 : kp3;
        pa[kk] = pu.v;
      }

      __builtin_amdgcn_s_setprio(1);
#pragma unroll
      for (int kk = 0; kk < 2; ++kk) {
#pragma unroll
        for (int f = 0; f < 8; ++f) {
          int d = f * 16 + r16;
          short8 vf = *(const short8*)__builtin_assume_aligned(
              &Vsm[b][d * 64 + ((kk * 32 + kg * 8) ^ ((d & 7) << 3))], 16);
          o[f] = __builtin_amdgcn_mfma_f32_16x16x32_bf16(pa[kk], vf, o[f], 0, 0, 0);
        }
      }
      __builtin_amdgcn_s_setprio(0);
    }

    float inv = 1.f / lrow;
    float invj[4];
#pragma unroll
    for (int j = 0; j < 4; ++j) invj[j] = __shfl(inv, kg * 4 + j);
#pragma unroll
    for (int j = 0; j < 4; ++j) {
      int row = q0 + w * 16 + kg * 4 + j;
      unsigned short* yr = Y + (size_t)row * 4096 + h * 128;
#pragma unroll
      for (int f = 0; f < 8; ++f) yr[f * 16 + r16] = f2bf(o[f][j] * invj[j]);
    }
  };

  const int pr = blockIdx.x;
  process(pr * 64);
  process((31 - pr) * 64);
}

extern "C" void kernel_launch(void* const* d_in, const int* in_sizes, int n_in,
                              void* d_out, int out_size, void* d_ws, size_t ws_size,
                              hipStream_t stream) {
  const float* x      = (const float*)d_in[0];
  const float* cosb   = (const float*)d_in[1];
  const float* sinb   = (const float*)d_in[2];
  const float* w_attn = (const float*)d_in[3];
  const float* w_proj = (const float*)d_in[4];
  float* out = (float*)d_out;

  char* ws = (char*)d_ws;
  const size_t MB = 1024 * 1024;
  unsigned short* Xb  = (unsigned short*)(ws);
  unsigned short* Wa  = (unsigned short*)(ws + 16 * MB);
  unsigned short* Wp  = (unsigned short*)(ws);            // after gemm1
  unsigned short* Qb  = (unsigned short*)(ws + 32 * MB);  // after gemm1
  unsigned short* Kb  = (unsigned short*)(ws + 48 * MB);  // after gemm1
  unsigned short* Vt  = (unsigned short*)(ws + 52 * MB);  // after gemm1
  unsigned short* qkv = (unsigned short*)(ws + 64 * MB);
  unsigned short* Yb  = (unsigned short*)(ws + 64 * MB);  // after rope+transpose

  f32_to_bf16<<<4096, 256, 0, stream>>>(x, Xb, 2048 * 4096 / 8);
  f32_to_bf16<<<12288, 256, 0, stream>>>(w_attn, Wa, 6144 * 4096 / 8);
  gemm_qkv<<<256, 512, 0, stream>>>(Xb, Wa, qkv, 2048, 6144, 4096);
  rope_qk<<<20480, 256, 0, stream>>>(qkv, cosb, sinb, Qb, Kb);
  transpose_v<<<dim3(32, 8), 256, 0, stream>>>(qkv, Vt);
  f32_to_bf16<<<8192, 256, 0, stream>>>(w_proj, Wp, 4096 * 4096 / 8);
  flash_attn<<<dim3(16, 32), 256, 0, stream>>>(Qb, Kb, Vt, Yb);
  gemm_proj<<<256, 512, 0, stream>>>(Yb, Wp, out, 2048, 4096, 4096);
}